// Round 10
// baseline (136.963 us; speedup 1.0000x reference)
//
#include <hip/hip_runtime.h>
#include <math.h>

#define C 10
#define BLOCK 256
#define NBLOCKS 1024          // 4 blocks/CU; ~3.8 row-pairs per thread, 2-deep pipeline
#define NSTATS (3 * C)        // 30 series: s1[10], s2[10], slogp[10]

typedef float f4 __attribute__((ext_vector_type(4)));   // native vector: OK for nontemporal builtins

// ---------------- row accumulate from registers ----------------

__device__ __forceinline__ void accum_vals(const float* __restrict__ v,
                                           float* __restrict__ s1,
                                           float* __restrict__ s2,
                                           float* __restrict__ sl) {
  float mx = v[0];
#pragma unroll
  for (int c = 1; c < C; c++) mx = fmaxf(mx, v[c]);
  float w[C], e[C], se = 0.f;
#pragma unroll
  for (int c = 0; c < C; c++) { w[c] = v[c] - mx; e[c] = __expf(w[c]); se += e[c]; }
  float inv = 1.0f / se;
  float lse = __logf(se);
#pragma unroll
  for (int c = 0; c < C; c++) {
    float p = e[c] * inv;
    s1[c] += p;
    s2[c] = fmaf(p, p, s2[c]);
    sl[c] += w[c] - lse;              // log p = (x - mx) - lse
  }
}

// ---------------- Kernel 1: direct-load deep-MLP stats ----------------
// Thread owns consecutive row PAIRS (80 B, 16 B aligned): 5 nontemporal dwordx4.
// 2-deep software pipeline -> 10 independent 1 KB wave-loads in flight, no
// barriers, no LDS in hot loop. nt streams past the poison-churned L2/L3.

__global__ __launch_bounds__(BLOCK) void dir_stats_kernel(
    const float* __restrict__ x, float* __restrict__ partials,
    int nrows, int nblocks) {
  const int tid = threadIdx.x;
  const int gid = blockIdx.x * BLOCK + tid;
  const int stride = nblocks * BLOCK;
  const int npairs = nrows >> 1;

  float s1[C], s2[C], sl[C];
#pragma unroll
  for (int c = 0; c < C; c++) { s1[c] = 0.f; s2[c] = 0.f; sl[c] = 0.f; }

  int g = gid;
  bool have = (g < npairs);
  f4 a0 = 0, a1 = 0, a2 = 0, a3 = 0, a4 = 0;
  if (have) {
    const f4* __restrict__ p = (const f4*)(x + (size_t)g * 20);
    a0 = __builtin_nontemporal_load(p);
    a1 = __builtin_nontemporal_load(p + 1);
    a2 = __builtin_nontemporal_load(p + 2);
    a3 = __builtin_nontemporal_load(p + 3);
    a4 = __builtin_nontemporal_load(p + 4);
  }
  while (have) {
    const int gn = g + stride;
    const bool haven = (gn < npairs);
    f4 b0 = 0, b1 = 0, b2 = 0, b3 = 0, b4 = 0;
    if (haven) {                      // prefetch next pair — overlaps compute below
      const f4* __restrict__ p = (const f4*)(x + (size_t)gn * 20);
      b0 = __builtin_nontemporal_load(p);
      b1 = __builtin_nontemporal_load(p + 1);
      b2 = __builtin_nontemporal_load(p + 2);
      b3 = __builtin_nontemporal_load(p + 3);
      b4 = __builtin_nontemporal_load(p + 4);
    }
    float v[20];
    v[0]=a0.x; v[1]=a0.y; v[2]=a0.z; v[3]=a0.w;
    v[4]=a1.x; v[5]=a1.y; v[6]=a1.z; v[7]=a1.w;
    v[8]=a2.x; v[9]=a2.y; v[10]=a2.z; v[11]=a2.w;
    v[12]=a3.x; v[13]=a3.y; v[14]=a3.z; v[15]=a3.w;
    v[16]=a4.x; v[17]=a4.y; v[18]=a4.z; v[19]=a4.w;
    accum_vals(v,      s1, s2, sl);
    accum_vals(v + 10, s1, s2, sl);
    a0 = b0; a1 = b1; a2 = b2; a3 = b3; a4 = b4;
    g = gn; have = haven;
  }

  // odd final row (nrows=2M is even; guard anyway)
  if ((nrows & 1) && gid == 0) {
    float v[C];
    const float* r = x + (size_t)(nrows - 1) * C;
#pragma unroll
    for (int c = 0; c < C; c++) v[c] = r[c];
    accum_vals(v, s1, s2, sl);
  }

  // block reduction: wave shuffle, then cross-wave via LDS
  const int lane = tid & 63;
  const int wave = tid >> 6;
  __shared__ float red[4][NSTATS];
#pragma unroll
  for (int c = 0; c < C; c++) {
    float v1 = s1[c], v2 = s2[c], v3 = sl[c];
#pragma unroll
    for (int off = 32; off >= 1; off >>= 1) {
      v1 += __shfl_down(v1, off);
      v2 += __shfl_down(v2, off);
      v3 += __shfl_down(v3, off);
    }
    if (lane == 0) {
      red[wave][c] = v1;
      red[wave][C + c] = v2;
      red[wave][2 * C + c] = v3;
    }
  }
  __syncthreads();
  if (tid < NSTATS) {
    float tot = red[0][tid] + red[1][tid] + red[2][tid] + red[3][tid];
    partials[(size_t)tid * nblocks + blockIdx.x] = tot;   // SoA over blocks
  }
}

// ---------------- Kernel 2: MLP-parallel reduce + Newton (fp64) ----------------

__device__ __forceinline__ void digtri8(double x, double& dg, double& tg) {
  double i0 = 1.0 / x,         i1 = 1.0 / (x + 1.0);
  double i2 = 1.0 / (x + 2.0), i3 = 1.0 / (x + 3.0);
  double i4 = 1.0 / (x + 4.0), i5 = 1.0 / (x + 5.0);
  double i6 = 1.0 / (x + 6.0), i7 = 1.0 / (x + 7.0);
  double rd = (i0 + i1) + (i2 + i3) + ((i4 + i5) + (i6 + i7));
  double rt = (i0 * i0 + i1 * i1) + (i2 * i2 + i3 * i3) +
              ((i4 * i4 + i5 * i5) + (i6 * i6 + i7 * i7));
  double y = x + 8.0;
  double yi = 1.0 / y, f = yi * yi;
  dg = log(y) - 0.5 * yi
     - f * (1.0 / 12 - f * (1.0 / 120 - f * (1.0 / 252 - f * (1.0 / 240 - f * (1.0 / 132)))))
     - rd;
  tg = rt + yi + 0.5 * f
     + f * yi * (1.0 / 6 - f * (1.0 / 30 - f * (1.0 / 42 - f * (1.0 / 30))));
}

__device__ __forceinline__ double wsum16(double v) {
#pragma unroll
  for (int off = 1; off < 16; off <<= 1) v += __shfl_xor(v, off);
  return v;
}

__global__ __launch_bounds__(1024) void dir_newton_kernel(
    const float* __restrict__ partials, float* __restrict__ out,
    int nparts, double nrows) {
  __shared__ double tot[NSTATS];
  const int tid = threadIdx.x;

  {
    const int j = tid >> 5;        // series (30 active of 32)
    const int k = tid & 31;
    double s = 0.0;
    if (j < NSTATS) {
      const float* __restrict__ base = partials + (size_t)j * nparts;
#pragma unroll 8
      for (int b = k; b < nparts; b += 32)
        s += (double)base[b];
    }
#pragma unroll
    for (int off = 16; off >= 1; off >>= 1) s += __shfl_xor(s, off);
    if (j < NSTATS && k == 0) tot[j] = s;
  }
  __syncthreads();

  if (tid < 16) {
    const int c = tid;
    const bool act = (c < C);
    const double n = nrows;
    double m1 = 0.0, m2 = 0.0, lpa = 0.0;
    if (act) {
      m1 = tot[c] / n;
      m2 = tot[C + c] / n;
      lpa = tot[2 * C + c] / n;
    }
    double ratio = act ? (m1 - m2) / (m2 - m1 * m1) : 0.0;
    double rmean = wsum16(ratio) / (double)C;
    double a = act ? m1 * rmean : 0.0;

    double diff = 1e30;
    for (int k = 0; k < 100 && diff >= 1e-3; k++) {
      double S = wsum16(a);             // lanes 10..15 hold 0
      double dgl, tgl;                  // lanes 0..9: digtri(a); lane 10+: digtri(S)
      digtri8(act ? a : S, dgl, tgl);
      double dgS = __shfl(dgl, 10);
      double tgS = __shfl(tgl, 10);
      double g = act ? (dgS - dgl + lpa) * n : 0.0;
      double qinv = act ? (-1.0) / (n * tgl) : 0.0;
      double z = n * tgS;
      double num = wsum16(g * qinv);
      double den = 1.0 / z + wsum16(qinv);
      double b = num / den;
      double anew = act ? a - (g - b) * qinv : 0.0;
      diff = wsum16(fabs(anew - a));
      a = anew;
    }
    if (act) out[c] = (float)a;
  }
}

// ---------------- launch ----------------

extern "C" void kernel_launch(void* const* d_in, const int* in_sizes, int n_in,
                              void* d_out, int out_size, void* d_ws, size_t ws_size,
                              hipStream_t stream) {
  const float* x = (const float*)d_in[0];
  const int total = in_sizes[0];
  const int nrows = total / C;

  int grid = NBLOCKS;
  size_t need = (size_t)NSTATS * grid * sizeof(float);
  if (need > ws_size) {
    grid = (int)(ws_size / (NSTATS * sizeof(float)));
    if (grid < 1) grid = 1;
  }

  float* partials = (float*)d_ws;
  dir_stats_kernel<<<grid, BLOCK, 0, stream>>>(x, partials, nrows, grid);
  dir_newton_kernel<<<1, 1024, 0, stream>>>(partials, (float*)d_out, grid, (double)nrows);
}

// Round 11
// 121.981 us; speedup vs baseline: 1.1228x; 1.1228x over previous
//
#include <hip/hip_runtime.h>
#include <math.h>

#define C 10
#define BLOCK 256
#define NBLOCKS 1024
#define WROWS 128                    // rows per wave-tile
#define WELEMS (WROWS * C)           // 1280 floats = 5 KB per buffer
#define NSTATS (3 * C)               // 30 series

typedef float f4 __attribute__((ext_vector_type(4)));

// ---------------- row accumulate (softmax sufficient statistics) ----------------

__device__ __forceinline__ void accum_row(const float* __restrict__ row,
                                          float* __restrict__ s1,
                                          float* __restrict__ s2,
                                          float* __restrict__ sl) {
  float v[C];
#pragma unroll
  for (int c = 0; c < C; c++) v[c] = row[c];
  float mx = v[0];
#pragma unroll
  for (int c = 1; c < C; c++) mx = fmaxf(mx, v[c]);
  float e[C], se = 0.f;
#pragma unroll
  for (int c = 0; c < C; c++) { v[c] -= mx; e[c] = __expf(v[c]); se += e[c]; }
  float inv = 1.0f / se;
  float lse = __logf(se);
#pragma unroll
  for (int c = 0; c < C; c++) {
    float p = e[c] * inv;
    s1[c] += p;
    s2[c] = fmaf(p, p, s2[c]);
    sl[c] += v[c] - lse;             // log p = (x - mx) - lse
  }
}

// ---------------- Kernel 1: wave-private staged stats — ZERO barriers in hot loop ----
// Each wave owns a private 2x5KB LDS double-buffer and grid-strides over 128-row
// wave-tiles. Stage = 5 coalesced dwordx4 per lane; next tile's loads are issued
// before compute so they fly across it. No inter-wave coupling -> no convoying.

__global__ __launch_bounds__(BLOCK) void dir_stats_kernel(
    const float* __restrict__ x, float* __restrict__ partials,
    int nrows, int nblocks) {
  __shared__ float buf[4][2][WELEMS];        // 4 waves x 2 phases x 5 KB = 40 KB
  __shared__ float red[4][NSTATS];
  const int tid = threadIdx.x;
  const int lane = tid & 63;
  const int wave = tid >> 6;

  const int gwave = blockIdx.x * 4 + wave;   // global wave id
  const int wstride = nblocks * 4;
  const int ntiles = nrows / WROWS;
  const int tailStart = ntiles * WROWS;

  float s1[C], s2[C], sl[C];
#pragma unroll
  for (int c = 0; c < C; c++) { s1[c] = 0.f; s2[c] = 0.f; sl[c] = 0.f; }

  int g = gwave;
  f4 a0 = 0, a1 = 0, a2 = 0, a3 = 0, a4 = 0;
  if (g < ntiles) {                          // prologue prefetch (coalesced 1 KB/step)
    const f4* __restrict__ p = (const f4*)(x + (size_t)g * WELEMS) + lane;
    a0 = p[0]; a1 = p[64]; a2 = p[128]; a3 = p[192]; a4 = p[256];
  }
  int phase = 0;
  while (g < ntiles) {
    f4* dst = (f4*)buf[wave][phase] + lane;  // wave-private: no barrier needed
    dst[0] = a0; dst[64] = a1; dst[128] = a2; dst[192] = a3; dst[256] = a4;

    const int gn = g + wstride;              // issue next tile's loads NOW
    if (gn < ntiles) {
      const f4* __restrict__ p = (const f4*)(x + (size_t)gn * WELEMS) + lane;
      a0 = p[0]; a1 = p[64]; a2 = p[128]; a3 = p[192]; a4 = p[256];
    }

    // same-wave ds ordering + compiler lgkm waits make this safe barrier-free
    accum_row(buf[wave][phase] + (size_t)lane * C, s1, s2, sl);
    accum_row(buf[wave][phase] + (size_t)(64 + lane) * C, s1, s2, sl);

    g = gn; phase ^= 1;
  }

  if (gwave == wstride - 1) {                // tail rows (none when nrows%128==0)
    for (int rr = tailStart + lane; rr < nrows; rr += 64) {
      float v[C];
      const float* r = x + (size_t)rr * C;
#pragma unroll
      for (int c = 0; c < C; c++) v[c] = r[c];
      float mx = v[0];
#pragma unroll
      for (int c = 1; c < C; c++) mx = fmaxf(mx, v[c]);
      float e[C], se = 0.f;
#pragma unroll
      for (int c = 0; c < C; c++) { v[c] -= mx; e[c] = __expf(v[c]); se += e[c]; }
      float inv = 1.0f / se, lse = __logf(se);
#pragma unroll
      for (int c = 0; c < C; c++) {
        float p = e[c] * inv;
        s1[c] += p; s2[c] = fmaf(p, p, s2[c]); sl[c] += v[c] - lse;
      }
    }
  }

  // block reduction: wave shuffle, then cross-wave via LDS (single barrier, post-loop)
#pragma unroll
  for (int c = 0; c < C; c++) {
    float v1 = s1[c], v2 = s2[c], v3 = sl[c];
#pragma unroll
    for (int off = 32; off >= 1; off >>= 1) {
      v1 += __shfl_down(v1, off);
      v2 += __shfl_down(v2, off);
      v3 += __shfl_down(v3, off);
    }
    if (lane == 0) {
      red[wave][c] = v1;
      red[wave][C + c] = v2;
      red[wave][2 * C + c] = v3;
    }
  }
  __syncthreads();
  if (tid < NSTATS) {
    float tot = red[0][tid] + red[1][tid] + red[2][tid] + red[3][tid];
    partials[(size_t)tid * nblocks + blockIdx.x] = tot;   // SoA over blocks
  }
}

// ---------------- Kernel 2: MLP-parallel reduce + Newton (fp64) ----------------

__device__ __forceinline__ void digtri8(double x, double& dg, double& tg) {
  double i0 = 1.0 / x,         i1 = 1.0 / (x + 1.0);
  double i2 = 1.0 / (x + 2.0), i3 = 1.0 / (x + 3.0);
  double i4 = 1.0 / (x + 4.0), i5 = 1.0 / (x + 5.0);
  double i6 = 1.0 / (x + 6.0), i7 = 1.0 / (x + 7.0);
  double rd = (i0 + i1) + (i2 + i3) + ((i4 + i5) + (i6 + i7));
  double rt = (i0 * i0 + i1 * i1) + (i2 * i2 + i3 * i3) +
              ((i4 * i4 + i5 * i5) + (i6 * i6 + i7 * i7));
  double y = x + 8.0;
  double yi = 1.0 / y, f = yi * yi;
  dg = log(y) - 0.5 * yi
     - f * (1.0 / 12 - f * (1.0 / 120 - f * (1.0 / 252 - f * (1.0 / 240 - f * (1.0 / 132)))))
     - rd;
  tg = rt + yi + 0.5 * f
     + f * yi * (1.0 / 6 - f * (1.0 / 30 - f * (1.0 / 42 - f * (1.0 / 30))));
}

__device__ __forceinline__ double wsum16(double v) {
#pragma unroll
  for (int off = 1; off < 16; off <<= 1) v += __shfl_xor(v, off);
  return v;
}

__global__ __launch_bounds__(1024) void dir_newton_kernel(
    const float* __restrict__ partials, float* __restrict__ out,
    int nparts, double nrows) {
  __shared__ double tot[NSTATS];
  const int tid = threadIdx.x;

  {
    const int j = tid >> 5;        // series (30 active of 32)
    const int k = tid & 31;
    double s = 0.0;
    if (j < NSTATS) {
      const float* __restrict__ base = partials + (size_t)j * nparts;
#pragma unroll 8
      for (int b = k; b < nparts; b += 32)
        s += (double)base[b];
    }
#pragma unroll
    for (int off = 16; off >= 1; off >>= 1) s += __shfl_xor(s, off);
    if (j < NSTATS && k == 0) tot[j] = s;
  }
  __syncthreads();

  if (tid < 16) {
    const int c = tid;
    const bool act = (c < C);
    const double n = nrows;
    double m1 = 0.0, m2 = 0.0, lpa = 0.0;
    if (act) {
      m1 = tot[c] / n;
      m2 = tot[C + c] / n;
      lpa = tot[2 * C + c] / n;
    }
    double ratio = act ? (m1 - m2) / (m2 - m1 * m1) : 0.0;
    double rmean = wsum16(ratio) / (double)C;
    double a = act ? m1 * rmean : 0.0;

    double diff = 1e30;
    for (int k = 0; k < 100 && diff >= 1e-3; k++) {
      double S = wsum16(a);             // lanes 10..15 hold 0
      double dgl, tgl;                  // lanes 0..9: digtri(a); lane 10+: digtri(S)
      digtri8(act ? a : S, dgl, tgl);
      double dgS = __shfl(dgl, 10);
      double tgS = __shfl(tgl, 10);
      double g = act ? (dgS - dgl + lpa) * n : 0.0;
      double qinv = act ? (-1.0) / (n * tgl) : 0.0;
      double z = n * tgS;
      double num = wsum16(g * qinv);
      double den = 1.0 / z + wsum16(qinv);
      double b = num / den;
      double anew = act ? a - (g - b) * qinv : 0.0;
      diff = wsum16(fabs(anew - a));
      a = anew;
    }
    if (act) out[c] = (float)a;
  }
}

// ---------------- launch ----------------

extern "C" void kernel_launch(void* const* d_in, const int* in_sizes, int n_in,
                              void* d_out, int out_size, void* d_ws, size_t ws_size,
                              hipStream_t stream) {
  const float* x = (const float*)d_in[0];
  const int total = in_sizes[0];
  const int nrows = total / C;

  int grid = NBLOCKS;
  size_t need = (size_t)NSTATS * grid * sizeof(float);
  if (need > ws_size) {
    grid = (int)(ws_size / (NSTATS * sizeof(float)));
    if (grid < 1) grid = 1;
  }

  float* partials = (float*)d_ws;
  dir_stats_kernel<<<grid, BLOCK, 0, stream>>>(x, partials, nrows, grid);
  dir_newton_kernel<<<1, 1024, 0, stream>>>(partials, (float*)d_out, grid, (double)nrows);
}